// Round 3
// baseline (858.698 us; speedup 1.0000x reference)
//
#include <hip/hip_runtime.h>

#define N_NODES 50000
#define DIM     128
#define E_EDGES 800000

// ---------------- CSR build ----------------

__global__ __launch_bounds__(256) void count_kernel(const int* __restrict__ edges,
                                                    int* __restrict__ cnt){
  int e = blockIdx.x * 256 + threadIdx.x;
  if (e < E_EDGES) atomicAdd(&cnt[edges[E_EDGES + e]], 1);
}

__global__ __launch_bounds__(256) void dinv_kernel(const int* __restrict__ cnt,
                                                   float* __restrict__ dinv){
  int i = blockIdx.x * 256 + threadIdx.x;
  if (i < N_NODES) dinv[i] = rsqrtf((float)(cnt[i] + 1));  // +1 self-loop; deg>0 always
}

// single-block exclusive scan of cnt[N] -> off[N+1], copy into cur[]
__global__ __launch_bounds__(1024) void scan_kernel(const int* __restrict__ cnt,
                                                    int* __restrict__ off,
                                                    int* __restrict__ cur){
  __shared__ int lds[1024];
  const int CH = (N_NODES + 1023) / 1024;  // 49
  int t = threadIdx.x;
  int base = t * CH;
  int s = 0;
  for (int j = 0; j < CH; ++j){ int idx = base + j; if (idx < N_NODES) s += cnt[idx]; }
  lds[t] = s;
  __syncthreads();
  for (int d = 1; d < 1024; d <<= 1){
    int v = (t >= d) ? lds[t - d] : 0;
    __syncthreads();
    lds[t] += v;
    __syncthreads();
  }
  int run = lds[t] - s;  // exclusive prefix
  for (int j = 0; j < CH; ++j){
    int idx = base + j;
    if (idx < N_NODES){ off[idx] = run; cur[idx] = run; run += cnt[idx]; }
  }
  if (t == 0) off[N_NODES] = E_EDGES;
}

__global__ __launch_bounds__(256) void fill_kernel(const int* __restrict__ edges,
                                                   int* __restrict__ cur,
                                                   const float* __restrict__ dinv,
                                                   int* __restrict__ csr_src,
                                                   float* __restrict__ csr_w){
  int e = blockIdx.x * 256 + threadIdx.x;
  if (e < E_EDGES){
    int s = edges[e];
    int d = edges[E_EDGES + e];
    int pos = atomicAdd(&cur[d], 1);
    csr_src[pos] = s;
    csr_w[pos]   = dinv[s] * dinv[d];
  }
}

// ---------------- LayerNorm + ReLU (standalone, for input x) ----------------
// One wave per row. Lane l owns cols 2l, 2l+1 (one float2).

__global__ __launch_bounds__(256) void ln0_kernel(const float* __restrict__ x,
                                                  const float* __restrict__ g,
                                                  const float* __restrict__ bt,
                                                  float* __restrict__ hn){
  int wid  = (blockIdx.x * 256 + threadIdx.x) >> 6;
  int lane = threadIdx.x & 63;
  if (wid >= N_NODES) return;
  float2 v = ((const float2*)x)[(size_t)wid * 64 + lane];
  float s = v.x + v.y, ss = v.x * v.x + v.y * v.y;
  #pragma unroll
  for (int d = 32; d >= 1; d >>= 1){ s += __shfl_xor(s, d, 64); ss += __shfl_xor(ss, d, 64); }
  float mu  = s * (1.0f / 128.0f);
  float var = ss * (1.0f / 128.0f) - mu * mu;
  float rs  = rsqrtf(var + 1e-5f);
  float2 ug = ((const float2*)g)[lane];
  float2 ub = ((const float2*)bt)[lane];
  float2 h;
  h.x = fmaxf((v.x - mu) * rs * ug.x + ub.x, 0.0f);
  h.y = fmaxf((v.y - mu) * rs * ug.y + ub.y, 0.0f);
  ((float2*)hn)[(size_t)wid * 64 + lane] = h;
}

// ---------------- GEMM (fp32 VALU): Y[row][n] = sum_k A[row][k] * W[k][n] ----------------
// W stays k-major. One wave per row (grid-stride). Lane l owns output cols 2l, 2l+1.
// A-row elements broadcast across the wave via __shfl.

__global__ __launch_bounds__(256) void gemm_valu(const float* __restrict__ A,
                                                 const float* __restrict__ W,
                                                 float* __restrict__ Y){
  __shared__ float ldsw[128 * 128];  // 64 KB
  int tid = threadIdx.x;
  const float4* W4 = (const float4*)W;
  #pragma unroll
  for (int it = 0; it < 16; ++it)
    ((float4*)ldsw)[tid + it * 256] = W4[tid + it * 256];
  __syncthreads();
  int wave = tid >> 6, lane = tid & 63;
  const float2* ldsw2 = (const float2*)ldsw;
  for (int row = blockIdx.x * 4 + wave; row < N_NODES; row += gridDim.x * 4){
    float2 a = ((const float2*)A)[(size_t)row * 64 + lane];  // A[row][2l], A[row][2l+1]
    float accx = 0.f, accy = 0.f;
    #pragma unroll 8
    for (int kp = 0; kp < 64; ++kp){
      float ae = __shfl(a.x, kp, 64);                 // A[row][2*kp]
      float ao = __shfl(a.y, kp, 64);                 // A[row][2*kp+1]
      float2 w0 = ldsw2[(2 * kp)     * 64 + lane];    // W[2kp][2l], W[2kp][2l+1]
      float2 w1 = ldsw2[(2 * kp + 1) * 64 + lane];    // W[2kp+1][..]
      accx += ae * w0.x + ao * w1.x;
      accy += ae * w0.y + ao * w1.y;
    }
    float2 o; o.x = accx; o.y = accy;
    ((float2*)Y)[(size_t)row * 64 + lane] = o;
  }
}

// ---------------- Aggregate (+bias, +residual, optional fused LN+ReLU) ----------------

template<bool HAS_RES, bool DO_LN>
__global__ __launch_bounds__(256) void agg_kernel(const float* __restrict__ y,
                                                  const int* __restrict__ off,
                                                  const int* __restrict__ csr_src,
                                                  const float* __restrict__ csr_w,
                                                  const float* __restrict__ dinv,
                                                  const float* __restrict__ bias,
                                                  const float* __restrict__ res,
                                                  float* __restrict__ outp,
                                                  const float* __restrict__ lng,
                                                  const float* __restrict__ lnb,
                                                  float* __restrict__ hn_out){
  int wid  = (blockIdx.x * 256 + threadIdx.x) >> 6;
  int lane = threadIdx.x & 63;
  if (wid >= N_NODES) return;
  const float2* y2 = (const float2*)y;

  float di = dinv[wid];
  float ws = di * di;                               // self-loop weight
  float2 us = y2[(size_t)wid * 64 + lane];
  float a0 = ws * us.x;
  float a1 = ws * us.y;

  int e  = off[wid];
  int e1 = off[wid + 1];
  for (; e + 1 < e1; e += 2){
    int   s0 = csr_src[e],   s1 = csr_src[e + 1];
    float w0 = csr_w[e],     w1 = csr_w[e + 1];
    float2 u0 = y2[(size_t)s0 * 64 + lane];
    float2 u1 = y2[(size_t)s1 * 64 + lane];
    a0 += w0 * u0.x; a1 += w0 * u0.y;
    a0 += w1 * u1.x; a1 += w1 * u1.y;
  }
  if (e < e1){
    int s0 = csr_src[e]; float w0 = csr_w[e];
    float2 u0 = y2[(size_t)s0 * 64 + lane];
    a0 += w0 * u0.x; a1 += w0 * u0.y;
  }

  float2 ub2 = ((const float2*)bias)[lane];
  a0 += ub2.x; a1 += ub2.y;
  if (HAS_RES){
    float2 ur = ((const float2*)res)[(size_t)wid * 64 + lane];
    a0 += ur.x; a1 += ur.y;
  }
  if (outp){
    float2 o; o.x = a0; o.y = a1;
    ((float2*)outp)[(size_t)wid * 64 + lane] = o;
  }

  if (DO_LN){
    float s = a0 + a1, ss = a0 * a0 + a1 * a1;
    #pragma unroll
    for (int d = 32; d >= 1; d >>= 1){ s += __shfl_xor(s, d, 64); ss += __shfl_xor(ss, d, 64); }
    float mu  = s * (1.0f / 128.0f);
    float var = ss * (1.0f / 128.0f) - mu * mu;
    float rs  = rsqrtf(var + 1e-5f);
    float2 ug = ((const float2*)lng)[lane];
    float2 ubb = ((const float2*)lnb)[lane];
    float2 h;
    h.x = fmaxf((a0 - mu) * rs * ug.x + ubb.x, 0.0f);
    h.y = fmaxf((a1 - mu) * rs * ug.y + ubb.y, 0.0f);
    ((float2*)hn_out)[(size_t)wid * 64 + lane] = h;
  }
}

// ---------------- launch ----------------

extern "C" void kernel_launch(void* const* d_in, const int* in_sizes, int n_in,
                              void* d_out, int out_size, void* d_ws, size_t ws_size,
                              hipStream_t stream){
  const float* x    = (const float*)d_in[0];
  const int*   edges= (const int*)d_in[1];
  const float* lng0 = (const float*)d_in[2];
  const float* lnb0 = (const float*)d_in[3];
  const float* W0   = (const float*)d_in[4];
  const float* b0   = (const float*)d_in[5];
  const float* lng1 = (const float*)d_in[6];
  const float* lnb1 = (const float*)d_in[7];
  const float* W1   = (const float*)d_in[8];
  const float* b1   = (const float*)d_in[9];
  const float* lng2 = (const float*)d_in[10];
  const float* lnb2 = (const float*)d_in[11];
  const float* W2   = (const float*)d_in[12];
  const float* b2   = (const float*)d_in[13];

  char* p = (char*)d_ws;
  auto carve = [&](size_t bytes) -> void* {
    void* r = (void*)p;
    p += (bytes + 255) & ~(size_t)255;
    return r;
  };
  int*   cnt     = (int*)  carve(N_NODES * 4);
  float* dinv    = (float*)carve(N_NODES * 4);
  int*   off     = (int*)  carve((N_NODES + 1) * 4);
  int*   cur     = (int*)  carve(N_NODES * 4);
  int*   csr_src = (int*)  carve((size_t)E_EDGES * 4);
  float* csr_w   = (float*)carve((size_t)E_EDGES * 4);
  float* hn      = (float*)carve((size_t)N_NODES * 128 * 4);
  float* yb      = (float*)carve((size_t)N_NODES * 128 * 4);
  float* out     = (float*)d_out;   // also doubles as x1 storage (layer-0 residual)

  hipMemsetAsync(cnt, 0, N_NODES * 4, stream);

  count_kernel<<<(E_EDGES + 255) / 256, 256, 0, stream>>>(edges, cnt);
  dinv_kernel<<<(N_NODES + 255) / 256, 256, 0, stream>>>(cnt, dinv);
  scan_kernel<<<1, 1024, 0, stream>>>(cnt, off, cur);
  fill_kernel<<<(E_EDGES + 255) / 256, 256, 0, stream>>>(edges, cur, dinv, csr_src, csr_w);

  const int GEMM_GRID = 2048;                   // grid-stride, 4 waves/block
  const int ROW_GRID  = (N_NODES + 3) / 4;      // 12500 blocks = 50000 waves

  // layer 0: LN0(x) -> hn ; y = hn@W0 ; x1 = agg(y)+b0+x -> d_out ; fused LN1 -> hn
  ln0_kernel<<<ROW_GRID, 256, 0, stream>>>(x, lng0, lnb0, hn);
  gemm_valu<<<GEMM_GRID, 256, 0, stream>>>(hn, W0, yb);
  agg_kernel<true, true><<<ROW_GRID, 256, 0, stream>>>(yb, off, csr_src, csr_w, dinv,
                                                       b0, x, out, lng1, lnb1, hn);
  // layer 1: y = hn@W1 ; h1 = agg(y)+b1 (not materialized) ; fused LN2(h1) -> hn
  gemm_valu<<<GEMM_GRID, 256, 0, stream>>>(hn, W1, yb);
  agg_kernel<false, true><<<ROW_GRID, 256, 0, stream>>>(yb, off, csr_src, csr_w, dinv,
                                                        b1, nullptr, nullptr, lng2, lnb2, hn);
  // layer 2: y = hn@W2 ; out = agg(y)+b2+x1   (x1 read from d_out, overwritten in place)
  gemm_valu<<<GEMM_GRID, 256, 0, stream>>>(hn, W2, yb);
  agg_kernel<true, false><<<ROW_GRID, 256, 0, stream>>>(yb, off, csr_src, csr_w, dinv,
                                                        b2, out, out, nullptr, nullptr, nullptr);
}

// Round 4
// 362.608 us; speedup vs baseline: 2.3681x; 2.3681x over previous
//
#include <hip/hip_runtime.h>

#define N_NODES 50000
#define DIM     128
#define E_EDGES 800000

typedef __attribute__((ext_vector_type(8))) short short8;
typedef __attribute__((ext_vector_type(4))) float f32x4;

__device__ __forceinline__ float bflo(unsigned int u){ return __uint_as_float(u << 16); }
__device__ __forceinline__ float bfhi(unsigned int u){ return __uint_as_float(u & 0xFFFF0000u); }
__device__ __forceinline__ unsigned int f2bf(float f){
  unsigned int u = __float_as_uint(f);
  return (u + 0x7FFFu + ((u >> 16) & 1u)) >> 16;
}
__device__ __forceinline__ unsigned int pack2(float a, float b){
  return f2bf(a) | (f2bf(b) << 16);
}

// ---------------- CSR build ----------------

__global__ __launch_bounds__(256) void count_kernel(const int* __restrict__ edges,
                                                    int* __restrict__ cnt){
  int e = blockIdx.x * 256 + threadIdx.x;
  if (e < E_EDGES) atomicAdd(&cnt[edges[E_EDGES + e]], 1);
}

__global__ __launch_bounds__(256) void dinv_kernel(const int* __restrict__ cnt,
                                                   float* __restrict__ dinv){
  int i = blockIdx.x * 256 + threadIdx.x;
  if (i < N_NODES) dinv[i] = rsqrtf((float)(cnt[i] + 1));  // +1 self-loop
}

// scan stage 1: per-block (256-elem) sums
__global__ __launch_bounds__(256) void scan_sum_kernel(const int* __restrict__ cnt,
                                                       int* __restrict__ bsum){
  int i = blockIdx.x * 256 + threadIdx.x;
  int v = (i < N_NODES) ? cnt[i] : 0;
  #pragma unroll
  for (int d = 32; d >= 1; d >>= 1) v += __shfl_xor(v, d, 64);
  __shared__ int ws4[4];
  int wave = threadIdx.x >> 6, lane = threadIdx.x & 63;
  if (lane == 0) ws4[wave] = v;
  __syncthreads();
  if (threadIdx.x == 0) bsum[blockIdx.x] = ws4[0] + ws4[1] + ws4[2] + ws4[3];
}

// scan stage 2: exclusive scan of the <=256 block sums (1 block)
__global__ __launch_bounds__(256) void scan_part_kernel(const int* __restrict__ bsum,
                                                        int* __restrict__ boff,
                                                        int nblk,
                                                        int* __restrict__ off){
  __shared__ int lds[256];
  int t = threadIdx.x;
  int v = (t < nblk) ? bsum[t] : 0;
  lds[t] = v;
  __syncthreads();
  #pragma unroll
  for (int d = 1; d < 256; d <<= 1){
    int u = (t >= d) ? lds[t - d] : 0;
    __syncthreads();
    lds[t] += u;
    __syncthreads();
  }
  boff[t] = lds[t] - v;  // exclusive
  if (t == 0) off[N_NODES] = E_EDGES;
}

// scan stage 3: per-block exclusive scan + block offset -> off, cur
__global__ __launch_bounds__(256) void scan_final_kernel(const int* __restrict__ cnt,
                                                         const int* __restrict__ boff,
                                                         int* __restrict__ off,
                                                         int* __restrict__ cur){
  __shared__ int lds[256];
  int t = threadIdx.x;
  int i = blockIdx.x * 256 + t;
  int v = (i < N_NODES) ? cnt[i] : 0;
  lds[t] = v;
  __syncthreads();
  #pragma unroll
  for (int d = 1; d < 256; d <<= 1){
    int u = (t >= d) ? lds[t - d] : 0;
    __syncthreads();
    lds[t] += u;
    __syncthreads();
  }
  if (i < N_NODES){
    int excl = boff[blockIdx.x] + lds[t] - v;
    off[i] = excl;
    cur[i] = excl;
  }
}

__global__ __launch_bounds__(256) void fill_kernel(const int* __restrict__ edges,
                                                   int* __restrict__ cur,
                                                   const float* __restrict__ dinv,
                                                   int2* __restrict__ csr){
  int e = blockIdx.x * 256 + threadIdx.x;
  if (e < E_EDGES){
    int s = edges[e];
    int d = edges[E_EDGES + e];
    int pos = atomicAdd(&cur[d], 1);
    int2 pk; pk.x = s; pk.y = __float_as_int(dinv[s] * dinv[d]);
    csr[pos] = pk;
  }
}

// fp32 W[k][n] -> bf16 Wt[n][k]
__global__ __launch_bounds__(256) void cvtw_kernel(const float* __restrict__ W,
                                                   unsigned short* __restrict__ Wt){
  int idx = blockIdx.x * 256 + threadIdx.x;  // < 16384
  int k = idx >> 7, n = idx & 127;
  Wt[n * 128 + k] = (unsigned short)f2bf(W[idx]);
}

// ---------------- LayerNorm + ReLU on input x (fp32 in, bf16 out) ----------------

__global__ __launch_bounds__(256) void ln0_kernel(const float* __restrict__ x,
                                                  const float* __restrict__ g,
                                                  const float* __restrict__ bt,
                                                  unsigned short* __restrict__ hn){
  int wid  = (blockIdx.x * 256 + threadIdx.x) >> 6;
  int lane = threadIdx.x & 63;
  if (wid >= N_NODES) return;
  float2 v = ((const float2*)x)[(size_t)wid * 64 + lane];
  float s = v.x + v.y, ss = v.x * v.x + v.y * v.y;
  #pragma unroll
  for (int d = 32; d >= 1; d >>= 1){ s += __shfl_xor(s, d, 64); ss += __shfl_xor(ss, d, 64); }
  float mu  = s * (1.0f / 128.0f);
  float var = ss * (1.0f / 128.0f) - mu * mu;
  float rs  = rsqrtf(var + 1e-5f);
  float2 ug = ((const float2*)g)[lane];
  float2 ub = ((const float2*)bt)[lane];
  float h0 = fmaxf((v.x - mu) * rs * ug.x + ub.x, 0.0f);
  float h1 = fmaxf((v.y - mu) * rs * ug.y + ub.y, 0.0f);
  ((unsigned int*)hn)[(size_t)wid * 64 + lane] = pack2(h0, h1);
}

// ---------------- MFMA GEMM: Y[N,128](bf16) = A[N,128](bf16) @ W ; Wt is W^T [n][k] ----

__global__ __launch_bounds__(256) void gemm_mfma(const unsigned short* __restrict__ A,
                                                 const unsigned short* __restrict__ Wt,
                                                 unsigned short* __restrict__ Y){
  __shared__ unsigned short ldsb[128 * 136];  // Wt rows padded 128->136
  int tid = threadIdx.x;
  #pragma unroll
  for (int it = 0; it < 8; ++it){
    int c  = tid + it * 256;          // 2048 chunks of 8 shorts
    int n  = c >> 4, kc = c & 15;
    *(short8*)&ldsb[n * 136 + kc * 8] = *(const short8*)(Wt + n * 128 + kc * 8);
  }
  int wave = tid >> 6, lane = tid & 63, quad = lane >> 4, l15 = lane & 15;
  int rowbase = blockIdx.x * 128 + wave * 32;
  int rm0 = rowbase + l15;      if (rm0 > N_NODES - 1) rm0 = N_NODES - 1;
  int rm1 = rowbase + 16 + l15; if (rm1 > N_NODES - 1) rm1 = N_NODES - 1;

  short8 a0[4], a1[4];
  #pragma unroll
  for (int kk = 0; kk < 4; ++kk){
    a0[kk] = *(const short8*)(A + (size_t)rm0 * 128 + kk * 32 + quad * 8);
    a1[kk] = *(const short8*)(A + (size_t)rm1 * 128 + kk * 32 + quad * 8);
  }
  f32x4 acc[2][8];
  #pragma unroll
  for (int mt = 0; mt < 2; ++mt)
    #pragma unroll
    for (int nt = 0; nt < 8; ++nt) acc[mt][nt] = (f32x4){0.f, 0.f, 0.f, 0.f};
  __syncthreads();
  #pragma unroll
  for (int kk = 0; kk < 4; ++kk){
    #pragma unroll
    for (int nt = 0; nt < 8; ++nt){
      short8 b = *(const short8*)&ldsb[(nt * 16 + l15) * 136 + kk * 32 + quad * 8];
      acc[0][nt] = __builtin_amdgcn_mfma_f32_16x16x32_bf16(a0[kk], b, acc[0][nt], 0, 0, 0);
      acc[1][nt] = __builtin_amdgcn_mfma_f32_16x16x32_bf16(a1[kk], b, acc[1][nt], 0, 0, 0);
    }
  }
  #pragma unroll
  for (int mt = 0; mt < 2; ++mt)
    #pragma unroll
    for (int nt = 0; nt < 8; ++nt)
      #pragma unroll
      for (int r = 0; r < 4; ++r){
        int row = rowbase + mt * 16 + quad * 4 + r;
        if (row < N_NODES)
          Y[(size_t)row * 128 + nt * 16 + l15] = (unsigned short)f2bf(acc[mt][nt][r]);
      }
}

// ---------------- Aggregate bf16 gathers (+bias, +residual, optional fused LN+ReLU) ----

template<bool HAS_RES, bool DO_LN>
__global__ __launch_bounds__(256) void agg_kernel(const unsigned short* __restrict__ y,
                                                  const int* __restrict__ off,
                                                  const int2* __restrict__ csr,
                                                  const float* __restrict__ dinv,
                                                  const float* __restrict__ bias,
                                                  const float* __restrict__ res,
                                                  float* __restrict__ outp,
                                                  const float* __restrict__ lng,
                                                  const float* __restrict__ lnb,
                                                  unsigned short* __restrict__ hn_out){
  int wid  = (blockIdx.x * 256 + threadIdx.x) >> 6;
  int lane = threadIdx.x & 63;
  if (wid >= N_NODES) return;
  const unsigned int* y32 = (const unsigned int*)y;

  float di = dinv[wid];
  float ws = di * di;                               // self-loop weight
  unsigned int us = y32[(size_t)wid * 64 + lane];
  float a0 = ws * bflo(us);
  float a1 = ws * bfhi(us);

  int e  = off[wid];
  int e1 = off[wid + 1];
  for (; e + 3 < e1; e += 4){
    int2 p0 = csr[e], p1 = csr[e + 1], p2 = csr[e + 2], p3 = csr[e + 3];
    unsigned int u0 = y32[(size_t)p0.x * 64 + lane];
    unsigned int u1 = y32[(size_t)p1.x * 64 + lane];
    unsigned int u2 = y32[(size_t)p2.x * 64 + lane];
    unsigned int u3 = y32[(size_t)p3.x * 64 + lane];
    float w0 = __int_as_float(p0.y), w1 = __int_as_float(p1.y);
    float w2 = __int_as_float(p2.y), w3 = __int_as_float(p3.y);
    a0 += w0 * bflo(u0); a1 += w0 * bfhi(u0);
    a0 += w1 * bflo(u1); a1 += w1 * bfhi(u1);
    a0 += w2 * bflo(u2); a1 += w2 * bfhi(u2);
    a0 += w3 * bflo(u3); a1 += w3 * bfhi(u3);
  }
  for (; e < e1; ++e){
    int2 p0 = csr[e];
    unsigned int u0 = y32[(size_t)p0.x * 64 + lane];
    float w0 = __int_as_float(p0.y);
    a0 += w0 * bflo(u0); a1 += w0 * bfhi(u0);
  }

  float2 ub2 = ((const float2*)bias)[lane];
  a0 += ub2.x; a1 += ub2.y;
  if (HAS_RES){
    float2 ur = ((const float2*)res)[(size_t)wid * 64 + lane];
    a0 += ur.x; a1 += ur.y;
  }
  if (outp){
    float2 o; o.x = a0; o.y = a1;
    ((float2*)outp)[(size_t)wid * 64 + lane] = o;
  }

  if (DO_LN){
    float s = a0 + a1, ss = a0 * a0 + a1 * a1;
    #pragma unroll
    for (int d = 32; d >= 1; d >>= 1){ s += __shfl_xor(s, d, 64); ss += __shfl_xor(ss, d, 64); }
    float mu  = s * (1.0f / 128.0f);
    float var = ss * (1.0f / 128.0f) - mu * mu;
    float rs  = rsqrtf(var + 1e-5f);
    float2 ug = ((const float2*)lng)[lane];
    float2 ubb = ((const float2*)lnb)[lane];
    float h0 = fmaxf((a0 - mu) * rs * ug.x + ubb.x, 0.0f);
    float h1 = fmaxf((a1 - mu) * rs * ug.y + ubb.y, 0.0f);
    ((unsigned int*)hn_out)[(size_t)wid * 64 + lane] = pack2(h0, h1);
  }
}

// ---------------- launch ----------------

extern "C" void kernel_launch(void* const* d_in, const int* in_sizes, int n_in,
                              void* d_out, int out_size, void* d_ws, size_t ws_size,
                              hipStream_t stream){
  const float* x    = (const float*)d_in[0];
  const int*   edges= (const int*)d_in[1];
  const float* lng0 = (const float*)d_in[2];
  const float* lnb0 = (const float*)d_in[3];
  const float* W0   = (const float*)d_in[4];
  const float* b0   = (const float*)d_in[5];
  const float* lng1 = (const float*)d_in[6];
  const float* lnb1 = (const float*)d_in[7];
  const float* W1   = (const float*)d_in[8];
  const float* b1   = (const float*)d_in[9];
  const float* lng2 = (const float*)d_in[10];
  const float* lnb2 = (const float*)d_in[11];
  const float* W2   = (const float*)d_in[12];
  const float* b2   = (const float*)d_in[13];

  char* p = (char*)d_ws;
  auto carve = [&](size_t bytes) -> void* {
    void* r = (void*)p;
    p += (bytes + 255) & ~(size_t)255;
    return r;
  };
  const int SBLK = (N_NODES + 255) / 256;          // 196 scan blocks
  int*   cnt   = (int*)  carve(N_NODES * 4);
  float* dinv  = (float*)carve(N_NODES * 4);
  int*   off   = (int*)  carve((N_NODES + 1) * 4);
  int*   cur   = (int*)  carve(N_NODES * 4);
  int*   bsum  = (int*)  carve(256 * 4);
  int*   boff  = (int*)  carve(256 * 4);
  int2*  csr   = (int2*) carve((size_t)E_EDGES * 8);
  unsigned short* Wt = (unsigned short*)carve(3 * 128 * 128 * 2);
  unsigned short* hn = (unsigned short*)carve((size_t)N_NODES * 128 * 2);
  unsigned short* yb = (unsigned short*)carve((size_t)N_NODES * 128 * 2);
  float* out = (float*)d_out;   // doubles as x1 storage (layer-0 residual output)

  hipMemsetAsync(cnt, 0, N_NODES * 4, stream);

  count_kernel<<<(E_EDGES + 255) / 256, 256, 0, stream>>>(edges, cnt);
  dinv_kernel<<<SBLK, 256, 0, stream>>>(cnt, dinv);
  scan_sum_kernel<<<SBLK, 256, 0, stream>>>(cnt, bsum);
  scan_part_kernel<<<1, 256, 0, stream>>>(bsum, boff, SBLK, off);
  scan_final_kernel<<<SBLK, 256, 0, stream>>>(cnt, boff, off, cur);
  fill_kernel<<<(E_EDGES + 255) / 256, 256, 0, stream>>>(edges, cur, dinv, csr);
  cvtw_kernel<<<64, 256, 0, stream>>>(W0, Wt);
  cvtw_kernel<<<64, 256, 0, stream>>>(W1, Wt + 16384);
  cvtw_kernel<<<64, 256, 0, stream>>>(W2, Wt + 32768);

  const int GEMM_GRID = (N_NODES + 127) / 128;  // 391
  const int ROW_GRID  = (N_NODES + 3) / 4;      // 12500 blocks = 50000 waves

  // layer 0: LN0(x) -> hn ; y = hn@W0 ; x1 = agg(y)+b0+x -> d_out ; fused LN1 -> hn
  ln0_kernel<<<ROW_GRID, 256, 0, stream>>>(x, lng0, lnb0, hn);
  gemm_mfma<<<GEMM_GRID, 256, 0, stream>>>(hn, Wt, yb);
  agg_kernel<true, true><<<ROW_GRID, 256, 0, stream>>>(yb, off, csr, dinv,
                                                       b0, x, out, lng1, lnb1, hn);
  // layer 1: y = hn@W1 ; h1 = agg(y)+b1 (not materialized) ; fused LN2(h1) -> hn
  gemm_mfma<<<GEMM_GRID, 256, 0, stream>>>(hn, Wt + 16384, yb);
  agg_kernel<false, true><<<ROW_GRID, 256, 0, stream>>>(yb, off, csr, dinv,
                                                        b1, nullptr, nullptr, lng2, lnb2, hn);
  // layer 2: y = hn@W2 ; out = agg(y)+b2+x1  (x1 read from d_out, overwritten in place)
  gemm_mfma<<<GEMM_GRID, 256, 0, stream>>>(hn, Wt + 32768, yb);
  agg_kernel<true, false><<<ROW_GRID, 256, 0, stream>>>(yb, off, csr, dinv,
                                                        b2, out, out, nullptr, nullptr, nullptr);
}